// Round 1
// baseline (2343.195 us; speedup 1.0000x reference)
//
#include <hip/hip_runtime.h>

// LSTM: B=65536 independent samples, L=6 layers, H=50, T=3, IN=3, then FC 50->1.
// Strategy: thread-per-sample (weights wave-uniform -> s_load broadcasts).
// h, x_t in registers (unrolled k); c, h_new in per-thread LDS rows (runtime j).
// Inter-layer sequence via global scratch ping-pong in d_ws ([t][k][b], coalesced).
// No inter-thread dependencies -> no barriers needed.

namespace {

constexpr int H   = 50;
constexpr int L   = 6;
constexpr int T   = 3;
constexpr int IN  = 3;
constexpr int BLK = 64;          // one wave per block; grid = B/64 = 1024 blocks
constexpr int ROW = 2 * H + 1;   // LDS row stride 101 dwords: (101*tid+j)%32 -> 2-way, free

__device__ __forceinline__ float fast_exp(float x) {
  return __builtin_amdgcn_exp2f(x * 1.44269504088896340736f);
}
__device__ __forceinline__ float sigm(float x) {
  // 1/(1+e^-x); rcp is ~1ulp, fine vs 6.25e-3 threshold. Saturates correctly at +-inf.
  return __builtin_amdgcn_rcpf(1.0f + fast_exp(-x));
}
__device__ __forceinline__ float tanh_(float x) {
  // tanh(x) = 1 - 2/(1+e^{2x}); saturates to +-1 on overflow/underflow of exp.
  return 1.0f - 2.0f * __builtin_amdgcn_rcpf(1.0f + fast_exp(2.0f * x));
}

// One LSTM timestep for one sample (one thread). Gate order: i,f,g,o (PyTorch).
template <int NIN>
__device__ __forceinline__ void lstm_step(
    const float* __restrict__ Wih,   // [4H][NIN] row-major
    const float* __restrict__ Whh,   // [4H][H]   row-major
    const float* __restrict__ bi,    // [4H]
    const float* __restrict__ bh,    // [4H]
    const float (&xt)[NIN],          // registers
    const float (&h)[H],             // registers (old h, read-only here)
    float* __restrict__ cT,          // LDS, per-thread row, stride 1
    float* __restrict__ hnT,         // LDS, per-thread row, stride 1
    float* __restrict__ ys_out,      // global: hn[j] -> ys_out[j*Bs] (coalesced over b)
    int Bs) {
#pragma unroll 1                     // keep body compact; ILP=4 from the 4 gate chains
  for (int j = 0; j < H; ++j) {
    float zi = bi[j]         + bh[j];
    float zf = bi[j + H]     + bh[j + H];
    float zg = bi[j + 2 * H] + bh[j + 2 * H];
    float zo = bi[j + 3 * H] + bh[j + 3 * H];
    const float* wi = Wih + j * NIN;
#pragma unroll
    for (int k = 0; k < NIN; ++k) {
      const float xk = xt[k];
      zi = fmaf(wi[k],                xk, zi);
      zf = fmaf(wi[k + H * NIN],      xk, zf);
      zg = fmaf(wi[k + 2 * H * NIN],  xk, zg);
      zo = fmaf(wi[k + 3 * H * NIN],  xk, zo);
    }
    const float* wh = Whh + j * H;
#pragma unroll
    for (int k = 0; k < H; ++k) {
      const float hk = h[k];
      zi = fmaf(wh[k],             hk, zi);
      zf = fmaf(wh[k + H * H],     hk, zf);
      zg = fmaf(wh[k + 2 * H * H], hk, zg);
      zo = fmaf(wh[k + 3 * H * H], hk, zo);
    }
    const float ig = sigm(zi);
    const float fg = sigm(zf);
    const float gg = tanh_(zg);
    const float og = sigm(zo);
    const float cv = fmaf(fg, cT[j], ig * gg);
    cT[j] = cv;
    const float hv = og * tanh_(cv);
    hnT[j] = hv;
    ys_out[(size_t)j * Bs] = hv;     // coalesced dword store across lanes
  }
}

__global__ __launch_bounds__(BLK, 1)   // grid gives 1 wave/SIMD; let VGPRs breathe (no spill)
void lstm_all(const float* __restrict__ x,      // [B,IN,T]
              const float* __restrict__ h0,     // [L,B,H]
              const float* __restrict__ c0,     // [L,B,H]
              const float* __restrict__ w_ih0,  // [4H,IN]
              const float* __restrict__ w_ihL,  // [L-1,4H,H]
              const float* __restrict__ w_hh,   // [L,4H,H]
              const float* __restrict__ b_ih,   // [L,4H]
              const float* __restrict__ b_hh,   // [L,4H]
              const float* __restrict__ fc_w,   // [H]
              const float* __restrict__ fc_b,   // [1]
              float* __restrict__ out,          // [B]
              float* __restrict__ ys0,          // scratch [T][H][B]
              float* __restrict__ ys1,          // scratch [T][H][B]
              int B) {
  const int b = blockIdx.x * BLK + threadIdx.x;
  __shared__ float lds[BLK][ROW];
  float* cT  = &lds[threadIdx.x][0];
  float* hnT = &lds[threadIdx.x][H];

  float h[H];

  // ---- input x for this sample: [IN][T], 9 floats ----
  float x9[IN * T];
#pragma unroll
  for (int i = 0; i < IN * T; ++i) x9[i] = x[(size_t)b * (IN * T) + i];

  // ---------------- layer 0 ----------------
#pragma unroll
  for (int k = 0; k < H; ++k) h[k] = h0[(size_t)b * H + k];
#pragma unroll
  for (int k = 0; k < H; ++k) cT[k] = c0[(size_t)b * H + k];

  for (int t = 0; t < T; ++t) {
    float xt[IN];
#pragma unroll
    for (int i = 0; i < IN; ++i) xt[i] = x9[i * T + t];  // x[b][i][t]
    lstm_step<IN>(w_ih0, w_hh, b_ih, b_hh, xt, h, cT, hnT,
                  ys0 + (size_t)t * H * B + b, B);
#pragma unroll
    for (int k = 0; k < H; ++k) h[k] = hnT[k];
  }

  // ---------------- layers 1..L-1 ----------------
  float* bufs[2] = {ys0, ys1};
  for (int l = 1; l < L; ++l) {
    const float* src = bufs[(l - 1) & 1];
    float* dst       = bufs[l & 1];
    const float* Wih = w_ihL + (size_t)(l - 1) * 4 * H * H;
    const float* Whh = w_hh  + (size_t)l * 4 * H * H;
    const float* bi  = b_ih + l * 4 * H;
    const float* bh  = b_hh + l * 4 * H;
#pragma unroll
    for (int k = 0; k < H; ++k) h[k] = h0[((size_t)l * B + b) * H + k];
#pragma unroll
    for (int k = 0; k < H; ++k) cT[k] = c0[((size_t)l * B + b) * H + k];

    for (int t = 0; t < T; ++t) {
      float xt[H];
#pragma unroll
      for (int k = 0; k < H; ++k) xt[k] = src[((size_t)t * H + k) * B + b];
      lstm_step<H>(Wih, Whh, bi, bh, xt, h, cT, hnT,
                   dst + (size_t)t * H * B + b, B);
#pragma unroll
      for (int k = 0; k < H; ++k) h[k] = hnT[k];
    }
  }

  // ---------------- fc: out[b] = dot(fc_w, h) + fc_b ----------------
  float acc = fc_b[0];
#pragma unroll
  for (int k = 0; k < H; ++k) acc = fmaf(fc_w[k], h[k], acc);
  out[b] = acc;
}

}  // namespace

extern "C" void kernel_launch(void* const* d_in, const int* in_sizes, int n_in,
                              void* d_out, int out_size, void* d_ws, size_t ws_size,
                              hipStream_t stream) {
  const float* x     = (const float*)d_in[0];
  const float* h0    = (const float*)d_in[1];
  const float* c0    = (const float*)d_in[2];
  const float* w_ih0 = (const float*)d_in[3];
  const float* w_ih  = (const float*)d_in[4];
  const float* w_hh  = (const float*)d_in[5];
  const float* b_ih  = (const float*)d_in[6];
  const float* b_hh  = (const float*)d_in[7];
  const float* fc_w  = (const float*)d_in[8];
  const float* fc_b  = (const float*)d_in[9];
  float* out         = (float*)d_out;

  const int B = in_sizes[0] / (IN * T);  // 65536

  // Scratch: two ping-pong ys buffers, [T][H][B] fp32 each = 39.3 MB -> 78.6 MB total.
  float* ys0 = (float*)d_ws;
  float* ys1 = ys0 + (size_t)T * H * B;

  lstm_all<<<B / BLK, BLK, 0, stream>>>(x, h0, c0, w_ih0, w_ih, w_hh, b_ih, b_hh,
                                        fc_w, fc_b, out, ys0, ys1, B);
}

// Round 2
// 1022.097 us; speedup vs baseline: 2.2925x; 2.2925x over previous
//
#include <hip/hip_runtime.h>

// LSTM: B=65536, L=6 layers, H=50, T=3, IN=3, FC 50->1.
// R2: wave-split hidden dim. Block = 64 samples (lanes) x 8 waves (j-chunks).
// - ys[T][H][64] in LDS, overwritten in place layer-by-layer (x_t consumed at
//   step t exactly when new h_t is produced).
// - c in LDS [H][64] (jj-loop rolled -> runtime index; keeps I-cache small).
// - x_t / h staged to registers once per step (100 ds_read per ~2600 FMA).
// - j0 via readfirstlane -> weight/bias loads stay wave-uniform s_loads.
// - launch_bounds(512,4): cap 128 VGPR -> 4 waves/SIMD, 16 waves/CU.

namespace {

constexpr int H     = 50;
constexpr int L     = 6;
constexpr int T     = 3;
constexpr int IN    = 3;
constexpr int LANES = 64;   // samples per block
constexpr int S     = 8;    // waves per block (j-split)
constexpr int BLK   = LANES * S;  // 512

__device__ __forceinline__ float fast_exp(float x) {
  return __builtin_amdgcn_exp2f(x * 1.44269504088896340736f);
}
__device__ __forceinline__ float sigm(float x) {
  return __builtin_amdgcn_rcpf(1.0f + fast_exp(-x));
}
__device__ __forceinline__ float tanh_(float x) {
  return 1.0f - 2.0f * __builtin_amdgcn_rcpf(1.0f + fast_exp(2.0f * x));
}

// Run one full layer (T timesteps) for this block's 64 samples.
// This wave handles gate-quads j in [j0, j0+cnt).
template <int NIN>
__device__ __forceinline__ void layer_run(
    const float* __restrict__ Wih,  // [4H][NIN] row-major (uniform)
    const float* __restrict__ Whh,  // [4H][H]   row-major (uniform)
    const float* __restrict__ bi,   // [4H] (uniform)
    const float* __restrict__ bh,   // [4H] (uniform)
    const float* __restrict__ xg,   // layer0 only: &x[b*IN*T] (per-thread)
    const float* __restrict__ h0g,  // &h0[(l*B+b)*H] (per-thread)
    const float* __restrict__ c0g,  // &c0[(l*B+b)*H] (per-thread)
    float* __restrict__ ys,         // LDS [T][H][LANES]
    float* __restrict__ cl,         // LDS [H][LANES]
    int lane, int j0, int cnt) {
  // init c for this wave's j rows (row ownership is per-wave; no extra sync)
  for (int jj = 0; jj < cnt; ++jj)
    cl[(j0 + jj) * LANES + lane] = c0g[j0 + jj];

#pragma unroll 1
  for (int t = 0; t < T; ++t) {
    // ---- stage h (recurrent input) into registers ----
    float hr[H];
    if (t == 0) {
#pragma unroll
      for (int k = 0; k < H; ++k) hr[k] = h0g[k];
    } else {
#pragma unroll
      for (int k = 0; k < H; ++k) hr[k] = ys[((t - 1) * H + k) * LANES + lane];
    }
    // ---- stage x_t into registers ----
    float xr[NIN];
    if constexpr (NIN == IN) {
#pragma unroll
      for (int i = 0; i < NIN; ++i) xr[i] = xg[i * T + t];  // x[b][i][t]
    } else {
#pragma unroll
      for (int k = 0; k < NIN; ++k) xr[k] = ys[(t * H + k) * LANES + lane];
    }
    __syncthreads();  // all stage-reads of ys[t] done before it is overwritten

#pragma unroll 1
    for (int jj = 0; jj < cnt; ++jj) {
      const int j = j0 + jj;
      float zi = bi[j]         + bh[j];
      float zf = bi[j + H]     + bh[j + H];
      float zg = bi[j + 2 * H] + bh[j + 2 * H];
      float zo = bi[j + 3 * H] + bh[j + 3 * H];
      const float* wi = Wih + j * NIN;
#pragma unroll
      for (int k = 0; k < NIN; ++k) {
        const float xk = xr[k];
        zi = fmaf(wi[k],               xk, zi);
        zf = fmaf(wi[k + H * NIN],     xk, zf);
        zg = fmaf(wi[k + 2 * H * NIN], xk, zg);
        zo = fmaf(wi[k + 3 * H * NIN], xk, zo);
      }
      const float* wh = Whh + j * H;
#pragma unroll
      for (int k = 0; k < H; ++k) {
        const float hk = hr[k];
        zi = fmaf(wh[k],             hk, zi);
        zf = fmaf(wh[k + H * H],     hk, zf);
        zg = fmaf(wh[k + 2 * H * H], hk, zg);
        zo = fmaf(wh[k + 3 * H * H], hk, zo);
      }
      const float ig = sigm(zi);
      const float fg = sigm(zf);
      const float gg = tanh_(zg);
      const float og = sigm(zo);
      const float cv = fmaf(fg, cl[j * LANES + lane], ig * gg);
      cl[j * LANES + lane] = cv;
      ys[(t * H + j) * LANES + lane] = og * tanh_(cv);  // new h_t
    }
    __syncthreads();  // ys[t] writes visible before next step's stage-reads
  }
}

__global__ __launch_bounds__(BLK, 4)
void lstm_all(const float* __restrict__ x,      // [B,IN,T]
              const float* __restrict__ h0,     // [L,B,H]
              const float* __restrict__ c0,     // [L,B,H]
              const float* __restrict__ w_ih0,  // [4H,IN]
              const float* __restrict__ w_ihL,  // [L-1,4H,H]
              const float* __restrict__ w_hh,   // [L,4H,H]
              const float* __restrict__ b_ih,   // [L,4H]
              const float* __restrict__ b_hh,   // [L,4H]
              const float* __restrict__ fc_w,   // [H]
              const float* __restrict__ fc_b,   // [1]
              float* __restrict__ out,          // [B]
              int B) {
  const int lane = threadIdx.x & (LANES - 1);
  const int w    = threadIdx.x >> 6;
  const int b    = blockIdx.x * LANES + lane;

  // force wave-uniform j-range into SGPRs so weight/bias loads are s_loads
  const int j0  = __builtin_amdgcn_readfirstlane((w * H) / S);
  const int j1  = __builtin_amdgcn_readfirstlane(((w + 1) * H) / S);
  const int cnt = j1 - j0;

  __shared__ float ys[T * H * LANES];  // 38400 B, [t][j][lane]
  __shared__ float cl[H * LANES];      // 12800 B, [j][lane]

  // ---------------- layer 0 ----------------
  layer_run<IN>(w_ih0, w_hh, b_ih, b_hh,
                x + (size_t)b * IN * T,
                h0 + (size_t)b * H,
                c0 + (size_t)b * H,
                ys, cl, lane, j0, cnt);

  // ---------------- layers 1..L-1 ----------------
#pragma unroll 1
  for (int l = 1; l < L; ++l) {
    layer_run<H>(w_ihL + (size_t)(l - 1) * 4 * H * H,
                 w_hh + (size_t)l * 4 * H * H,
                 b_ih + l * 4 * H,
                 b_hh + l * 4 * H,
                 nullptr,
                 h0 + ((size_t)l * B + b) * H,
                 c0 + ((size_t)l * B + b) * H,
                 ys, cl, lane, j0, cnt);
  }

  // ---------------- fc on last timestep's h (ys[T-1]) ----------------
  if (w == 0) {
    float acc = fc_b[0];
#pragma unroll
    for (int k = 0; k < H; ++k)
      acc = fmaf(fc_w[k], ys[((T - 1) * H + k) * LANES + lane], acc);
    out[b] = acc;
  }
}

}  // namespace

extern "C" void kernel_launch(void* const* d_in, const int* in_sizes, int n_in,
                              void* d_out, int out_size, void* d_ws, size_t ws_size,
                              hipStream_t stream) {
  const float* x     = (const float*)d_in[0];
  const float* h0    = (const float*)d_in[1];
  const float* c0    = (const float*)d_in[2];
  const float* w_ih0 = (const float*)d_in[3];
  const float* w_ih  = (const float*)d_in[4];
  const float* w_hh  = (const float*)d_in[5];
  const float* b_ih  = (const float*)d_in[6];
  const float* b_hh  = (const float*)d_in[7];
  const float* fc_w  = (const float*)d_in[8];
  const float* fc_b  = (const float*)d_in[9];
  float* out         = (float*)d_out;

  const int B = in_sizes[0] / (IN * T);  // 65536

  lstm_all<<<B / LANES, BLK, 0, stream>>>(x, h0, c0, w_ih0, w_ih, w_hh,
                                          b_ih, b_hh, fc_w, fc_b, out, B);
}